// Round 2
// baseline (4371.327 us; speedup 1.0000x reference)
//
#include <hip/hip_runtime.h>
#include <hip/hip_bf16.h>
#include <stdint.h>
#include <stddef.h>

// ---------------------------------------------------------------------------
// Threefry-2x32-20 (JAX), key = (0, 42)
// ---------------------------------------------------------------------------
__device__ __forceinline__ uint32_t rotl32(uint32_t x, int r) {
  return (x << r) | (x >> (32 - r));
}

__device__ __forceinline__ void threefry2x32(uint32_t x0, uint32_t x1,
                                             uint32_t& o0, uint32_t& o1) {
  const uint32_t k0 = 0u, k1 = 42u;
  const uint32_t k2 = k0 ^ k1 ^ 0x1BD11BDAu;
  x0 += k0; x1 += k1;
#define TF_ROUND(r) { x0 += x1; x1 = rotl32(x1, (r)); x1 ^= x0; }
  TF_ROUND(13) TF_ROUND(15) TF_ROUND(26) TF_ROUND(6)
  x0 += k1; x1 += k2 + 1u;
  TF_ROUND(17) TF_ROUND(29) TF_ROUND(16) TF_ROUND(24)
  x0 += k2; x1 += k0 + 2u;
  TF_ROUND(13) TF_ROUND(15) TF_ROUND(26) TF_ROUND(6)
  x0 += k0; x1 += k1 + 3u;
  TF_ROUND(17) TF_ROUND(29) TF_ROUND(16) TF_ROUND(24)
  x0 += k1; x1 += k2 + 4u;
  TF_ROUND(13) TF_ROUND(15) TF_ROUND(26) TF_ROUND(6)
  x0 += k2; x1 += k0 + 5u;
#undef TF_ROUND
  o0 = x0; o1 = x1;
}

// Gumbel(0,1) matching jax.random.uniform(key(42), (8,128,8192)) with
// jax_threefry_partitionable=True: bits[i] = o0 ^ o1 of threefry(k, (0, i)).
__device__ __forceinline__ float gumbel_at(uint32_t i) {
  uint32_t o0, o1;
  threefry2x32(0u, i, o0, o1);
  uint32_t bits = o0 ^ o1;
  float f = __uint_as_float((bits >> 9) | 0x3F800000u) - 1.0f;  // [0,1)
  float u = fmaxf(1e-20f, f + 1e-20f);                          // jax uniform epilogue
  return -logf(-logf(u));
}

// monotonic float->uint mapping (IEEE total order for finite values)
__device__ __forceinline__ uint32_t fmono(float v) {
  uint32_t b = __float_as_uint(v);
  return (b & 0x80000000u) ? ~b : (b | 0x80000000u);
}

// ---------------------------------------------------------------------------
// Generic f32 GEMM:  C[MxN] = act(A[MxK] @ W + bias),  W is KxN (or NxK if BT)
// DUAL: also write bf16 copy to C2 (same layout).
// GUMBEL: add gumbel_at(b*2^20 + col*2^13 + m) to each output (scores pass).
// block = 256 threads, (BM/TM)*(BN/TN) == 256
// ---------------------------------------------------------------------------
template<int BM, int BN, int BK, int TM, int TN,
         bool RELU, bool BT, bool HASBIAS, bool DUAL, bool GUMBEL>
__global__ __launch_bounds__(256) void gemm_kernel(
    const float* __restrict__ A, const float* __restrict__ W,
    const float* __restrict__ bias, float* __restrict__ C,
    __hip_bfloat16* __restrict__ C2,
    int M, int N, int K, int row_base)
{
  __shared__ __align__(16) float As[BK][BM + 4];
  __shared__ __align__(16) float Ws[BK][BN + 4];
  constexpr int TX = BN / TN;
  constexpr int TY = BM / TM;
  static_assert(TX * TY == 256, "bad tiling");
  constexpr int KV = BK / 4;

  const int tid = threadIdx.x;
  const int tx = tid % TX, ty = tid / TX;
  const int row0 = blockIdx.x * BM, col0 = blockIdx.y * BN;

  float acc[TM][TN];
#pragma unroll
  for (int i = 0; i < TM; ++i)
#pragma unroll
    for (int j = 0; j < TN; ++j) acc[i][j] = 0.0f;

  for (int k0 = 0; k0 < K; k0 += BK) {
    // --- stage A tile (transposed in LDS) ---
#pragma unroll
    for (int e = tid; e < BM * KV; e += 256) {
      int m = e / KV, kq = e % KV;
      float4 v = *reinterpret_cast<const float4*>(
          &A[(size_t)(row0 + m) * K + k0 + kq * 4]);
      As[kq * 4 + 0][m] = v.x; As[kq * 4 + 1][m] = v.y;
      As[kq * 4 + 2][m] = v.z; As[kq * 4 + 3][m] = v.w;
    }
    // --- stage W tile ---
    if (BT) {
#pragma unroll
      for (int e = tid; e < BN * KV; e += 256) {
        int c = e / KV, kq = e % KV;
        float4 v = *reinterpret_cast<const float4*>(
            &W[(size_t)(col0 + c) * K + k0 + kq * 4]);
        Ws[kq * 4 + 0][c] = v.x; Ws[kq * 4 + 1][c] = v.y;
        Ws[kq * 4 + 2][c] = v.z; Ws[kq * 4 + 3][c] = v.w;
      }
    } else {
      constexpr int CV = BN / 4;
#pragma unroll
      for (int e = tid; e < BK * CV; e += 256) {
        int kk = e / CV, c4 = e % CV;
        float4 v = *reinterpret_cast<const float4*>(
            &W[(size_t)(k0 + kk) * N + col0 + c4 * 4]);
        *reinterpret_cast<float4*>(&Ws[kk][c4 * 4]) = v;
      }
    }
    __syncthreads();

#pragma unroll
    for (int kk = 0; kk < BK; ++kk) {
      float a[TM], w[TN];
#pragma unroll
      for (int i4 = 0; i4 < TM / 4; ++i4)
        *reinterpret_cast<float4*>(&a[i4 * 4]) =
            *reinterpret_cast<const float4*>(&As[kk][ty * TM + i4 * 4]);
#pragma unroll
      for (int j4 = 0; j4 < TN / 4; ++j4)
        *reinterpret_cast<float4*>(&w[j4 * 4]) =
            *reinterpret_cast<const float4*>(&Ws[kk][tx * TN + j4 * 4]);
#pragma unroll
      for (int i = 0; i < TM; ++i)
#pragma unroll
        for (int j = 0; j < TN; ++j)
          acc[i][j] = fmaf(a[i], w[j], acc[i][j]);
    }
    __syncthreads();
  }

  // --- epilogue ---
#pragma unroll
  for (int i = 0; i < TM; ++i) {
    const int lrow = row0 + ty * TM + i;
    const size_t r = (size_t)lrow;
#pragma unroll
    for (int j4 = 0; j4 < TN / 4; ++j4) {
      int c = col0 + tx * TN + j4 * 4;
      float4 v = make_float4(acc[i][j4 * 4 + 0], acc[i][j4 * 4 + 1],
                             acc[i][j4 * 4 + 2], acc[i][j4 * 4 + 3]);
      if (HASBIAS) {
        v.x += bias[c + 0]; v.y += bias[c + 1];
        v.z += bias[c + 2]; v.w += bias[c + 3];
      }
      if (RELU) {
        v.x = fmaxf(v.x, 0.f); v.y = fmaxf(v.y, 0.f);
        v.z = fmaxf(v.z, 0.f); v.w = fmaxf(v.w, 0.f);
      }
      if (GUMBEL) {
        const int grow = row_base + lrow;           // global point row
        const uint32_t ib = ((uint32_t)(grow >> 13) << 20) | (uint32_t)(grow & 8191);
        v.x += gumbel_at(ib | ((uint32_t)(c + 0) << 13));
        v.y += gumbel_at(ib | ((uint32_t)(c + 1) << 13));
        v.z += gumbel_at(ib | ((uint32_t)(c + 2) << 13));
        v.w += gumbel_at(ib | ((uint32_t)(c + 3) << 13));
      }
      *reinterpret_cast<float4*>(&C[r * N + c]) = v;
      if (DUAL) {
        C2[r * N + c + 0] = __float2bfloat16(v.x);
        C2[r * N + c + 1] = __float2bfloat16(v.y);
        C2[r * N + c + 2] = __float2bfloat16(v.z);
        C2[r * N + c + 3] = __float2bfloat16(v.w);
      }
    }
  }
}

// ---------------------------------------------------------------------------
// Sequential Gumbel selection: 128 masked argmaxes per batch.
// sg is scores+gumbel in [b][m][k] layout; column reads are strided but the
// 4 MB per-batch slab stays L2-resident across the 128 steps.
// grid (8), block (1024). tie-break = lowest m (jnp.argmax semantics).
// ---------------------------------------------------------------------------
__global__ __launch_bounds__(1024) void select_tokens(
    const float* __restrict__ sg, int* __restrict__ sel_idx)
{
  const int b = blockIdx.x;
  const int tid = threadIdx.x;
  const int lane = tid & 63, wid = tid >> 6;
  __shared__ uint32_t avail[256];            // 8192-bit availability mask
  __shared__ unsigned long long wbest[16];
  if (tid < 256) avail[tid] = 0xFFFFFFFFu;
  __syncthreads();

  const float* base = sg + (size_t)b * 8192 * 128;
  for (int k = 0; k < 128; ++k) {
    unsigned long long loc = 0ull;
#pragma unroll
    for (int j = 0; j < 8; ++j) {
      int m = tid + j * 1024;
      uint32_t av = (avail[m >> 5] >> (m & 31)) & 1u;
      float v = base[(size_t)m * 128 + k];
      unsigned long long p =
          ((unsigned long long)fmono(v) << 13) | (unsigned long long)(8191 - m);
      if (av && p > loc) loc = p;
    }
#pragma unroll
    for (int off = 32; off; off >>= 1) {
      unsigned long long o = __shfl_down(loc, off);
      if (o > loc) loc = o;
    }
    if (lane == 0) wbest[wid] = loc;
    __syncthreads();
    if (tid < 64) {
      unsigned long long l = (tid < 16) ? wbest[tid] : 0ull;
#pragma unroll
      for (int off = 8; off; off >>= 1) {
        unsigned long long o = __shfl_down(l, off);
        if (o > l) l = o;
      }
      if (tid == 0) {
        int m = 8191 - (int)(l & 0x1FFFull);
        sel_idx[(b << 7) + k] = m;
        avail[m >> 5] &= ~(1u << (m & 31));
      }
    }
    __syncthreads();
  }
}

// ---------------------------------------------------------------------------
// Per selected token: d2 to all 8192 points (LDS), 16 argmin passes
// (tie-break = lowest index, matching lax.top_k), fused feature max-pool.
// grid (1024), block (256)
// ---------------------------------------------------------------------------
__global__ __launch_bounds__(256) void knn_pool(
    const float* __restrict__ coords,          // [65536][5]
    const __hip_bfloat16* __restrict__ pf,     // [65536][768] bf16
    const int* __restrict__ sel_idx,           // [8][128]
    float* __restrict__ pooled)                // [1024][768]
{
  const int q = blockIdx.x;       // b*128 + k
  const int b = q >> 7;
  const int tid = threadIdx.x;
  const int lane = tid & 63, wid = tid >> 6;
  __shared__ float d2s[8192];
  __shared__ int nbrs[16];
  __shared__ unsigned long long wb[4];

  const int sidx = sel_idx[q];
  const float* cbase = coords + (size_t)b * 8192 * 5;
  const float cx = cbase[sidx * 5 + 1];
  const float cy = cbase[sidx * 5 + 2];
  const float cz = cbase[sidx * 5 + 3];
  const float ss = cx * cx + cy * cy + cz * cz;

  for (int j = 0; j < 32; ++j) {
    int m = tid + j * 256;
    float px = cbase[m * 5 + 1], py = cbase[m * 5 + 2], pz = cbase[m * 5 + 3];
    d2s[m] = ss + (px * px + py * py + pz * pz)
               - 2.0f * (cx * px + cy * py + cz * pz);
  }
  __syncthreads();

  for (int it = 0; it < 16; ++it) {
    unsigned long long loc = ~0ull;
    for (int j = 0; j < 32; ++j) {
      int m = tid + j * 256;
      unsigned long long p =
          ((unsigned long long)fmono(d2s[m]) << 13) | (unsigned long long)m;
      if (p < loc) loc = p;
    }
#pragma unroll
    for (int off = 32; off; off >>= 1) {
      unsigned long long o = __shfl_down(loc, off);
      if (o < loc) loc = o;
    }
    if (lane == 0) wb[wid] = loc;
    __syncthreads();
    if (tid == 0) {
      unsigned long long best = wb[0];
      if (wb[1] < best) best = wb[1];
      if (wb[2] < best) best = wb[2];
      if (wb[3] < best) best = wb[3];
      int m = (int)(best & 0x1FFFull);
      nbrs[it] = m;
      d2s[m] = __uint_as_float(0x7F800000u);  // +inf: exclude from later passes
    }
    __syncthreads();
  }

  for (int d = tid; d < 768; d += 256) {
    float mx = -__uint_as_float(0x7F800000u);
#pragma unroll
    for (int it = 0; it < 16; ++it) {
      float v = __bfloat162float(pf[((size_t)b * 8192 + nbrs[it]) * 768 + d]);
      mx = fmaxf(mx, v);
    }
    pooled[(size_t)q * 768 + d] = mx;
  }
}

// ---------------------------------------------------------------------------
// Stable argsort of the 128 selected time-coords (rank counting), then write
// tokens = pf[sel] + agg (reordered), centroids, mask.
// grid (8), block (256)
// ---------------------------------------------------------------------------
__global__ __launch_bounds__(256) void finalize(
    const float* __restrict__ coords,
    const __hip_bfloat16* __restrict__ pf,
    const float* __restrict__ agg,       // [1024][768]
    const int* __restrict__ sel_idx,
    float* __restrict__ out)             // tokens | centroids | mask
{
  const int b = blockIdx.x;
  const int tid = threadIdx.x;
  __shared__ float tvals[128];
  __shared__ int rank[128];
  const float* cbase = coords + (size_t)b * 8192 * 5;

  if (tid < 128) tvals[tid] = cbase[sel_idx[(b << 7) + tid] * 5 + 4];
  __syncthreads();
  if (tid < 128) {
    float t = tvals[tid];
    int r = 0;
#pragma unroll 8
    for (int j = 0; j < 128; ++j) {
      float tj = tvals[j];
      r += (tj < t || (tj == t && j < tid)) ? 1 : 0;
    }
    rank[tid] = r;
  }
  __syncthreads();

  float* tokens = out;                       // 8*128*768
  float* cent   = out + 786432;              // 8*128*4
  float* mask   = out + 786432 + 4096;       // 8*128

  for (int i = 0; i < 128; ++i) {
    int r = rank[i];
    int sidx = sel_idx[(b << 7) + i];
    const __hip_bfloat16* src = pf + ((size_t)b * 8192 + sidx) * 768;
    const float* asrc = agg + (size_t)((b << 7) + i) * 768;
    float* dst = tokens + ((size_t)(b << 7) + r) * 768;
    for (int d = tid; d < 768; d += 256)
      dst[d] = __bfloat162float(src[d]) + asrc[d];
  }
  if (tid < 128) {
    int r = rank[tid];
    int sidx = sel_idx[(b << 7) + tid];
    cent[((b << 7) + r) * 4 + 0] = cbase[sidx * 5 + 1];
    cent[((b << 7) + r) * 4 + 1] = cbase[sidx * 5 + 2];
    cent[((b << 7) + r) * 4 + 2] = cbase[sidx * 5 + 3];
    cent[((b << 7) + r) * 4 + 3] = cbase[sidx * 5 + 4];
    mask[(b << 7) + tid] = 1.0f;
  }
}

// ---------------------------------------------------------------------------
// host launcher — compact, ws_size-adaptive workspace
// ---------------------------------------------------------------------------
extern "C" void kernel_launch(void* const* d_in, const int* in_sizes, int n_in,
                              void* d_out, int out_size, void* d_ws, size_t ws_size,
                              hipStream_t stream) {
  const float* coords = (const float*)d_in[0];
  const float* feats  = (const float*)d_in[1];
  const float* W1 = (const float*)d_in[2];  const float* b1 = (const float*)d_in[3];
  const float* W2 = (const float*)d_in[4];  const float* b2 = (const float*)d_in[5];
  const float* W3 = (const float*)d_in[6];  const float* b3 = (const float*)d_in[7];
  const float* W4 = (const float*)d_in[8];  const float* b4 = (const float*)d_in[9];
  const float* selw = (const float*)d_in[10];
  const float* nW1 = (const float*)d_in[11]; const float* nb1 = (const float*)d_in[12];
  const float* nW2 = (const float*)d_in[13]; const float* nb2 = (const float*)d_in[14];
  float* out = (float*)d_out;

  // workspace layout (persistent ~137.7 MB + chunk temps):
  //   pf_bf16 [65536x768]          96 MB
  //   scores+gumbel f32 [65536x128] 32 MB
  //   pooled / t1 / agg [1024x768]  3x3 MB
  //   sel idx [1024]                4 KB
  //   chunk temps h1/h2/h3/pfc      9216*Mc bytes
  const size_t PF_B = (size_t)65536 * 768 * 2;
  const size_t SC_B = (size_t)65536 * 128 * 4;
  const size_t PO_B = (size_t)1024 * 768 * 4;
  char* ws = (char*)d_ws;
  __hip_bfloat16* pf = (__hip_bfloat16*)ws;
  float* scores = (float*)(ws + PF_B);
  float* pooled = (float*)(ws + PF_B + SC_B);
  float* t1  = pooled + (size_t)1024 * 768;
  float* agg = t1 + (size_t)1024 * 768;
  int* sel = (int*)(agg + (size_t)1024 * 768);
  const size_t tmp_off = PF_B + SC_B + 3 * PO_B + 4096;

  int Mc = 512;
  const int cands[5] = {8192, 4096, 2048, 1024, 512};
  for (int ci = 0; ci < 5; ++ci) {
    if (tmp_off + (size_t)9216 * cands[ci] <= ws_size) { Mc = cands[ci]; break; }
  }
  float* h1  = (float*)(ws + tmp_off);
  float* h2  = h1 + (size_t)Mc * 256;
  float* h3  = h2 + (size_t)Mc * 512;
  float* pfc = h3 + (size_t)Mc * 768;

  dim3 blk(256);
  const int nC = 65536 / Mc;
  for (int c = 0; c < nC; ++c) {
    const int r0 = c * Mc;
    gemm_kernel<128,128,16,8,8,true ,false,true ,false,false>
      <<<dim3(Mc/128, 2), blk, 0, stream>>>(feats + (size_t)r0 * 32, W1, b1, h1, nullptr, Mc, 256, 32, 0);
    gemm_kernel<128,128,16,8,8,true ,false,true ,false,false>
      <<<dim3(Mc/128, 4), blk, 0, stream>>>(h1, W2, b2, h2, nullptr, Mc, 512, 256, 0);
    gemm_kernel<128,128,16,8,8,true ,false,true ,false,false>
      <<<dim3(Mc/128, 6), blk, 0, stream>>>(h2, W3, b3, h3, nullptr, Mc, 768, 512, 0);
    gemm_kernel<128,128,16,8,8,false,false,true ,true ,false>
      <<<dim3(Mc/128, 6), blk, 0, stream>>>(h3, W4, b4, pfc, pf + (size_t)r0 * 768, Mc, 768, 768, 0);
    // scores = pfc @ selw^T, + gumbel fused in epilogue
    gemm_kernel<128,128,16,8,8,false,true ,false,false,true >
      <<<dim3(Mc/128, 1), blk, 0, stream>>>(pfc, selw, nullptr, scores + (size_t)r0 * 128, nullptr, Mc, 128, 768, r0);
  }
  select_tokens<<<dim3(8), dim3(1024), 0, stream>>>(scores, sel);
  knn_pool<<<dim3(1024), blk, 0, stream>>>(coords, pf, sel, pooled);
  gemm_kernel<64,64,16,4,4,true ,false,true ,false,false>
    <<<dim3(16, 12), blk, 0, stream>>>(pooled, nW1, nb1, t1, nullptr, 1024, 768, 768, 0);
  gemm_kernel<64,64,16,4,4,false,false,true ,false,false>
    <<<dim3(16, 12), blk, 0, stream>>>(t1, nW2, nb2, agg, nullptr, 1024, 768, 768, 0);
  finalize<<<dim3(8), blk, 0, stream>>>(coords, pf, agg, sel, out);
}

// Round 3
// 2799.577 us; speedup vs baseline: 1.5614x; 1.5614x over previous
//
#include <hip/hip_runtime.h>
#include <hip/hip_bf16.h>
#include <stdint.h>
#include <stddef.h>

typedef unsigned long long u64;

// ---------------------------------------------------------------------------
// Threefry-2x32-20 (JAX), key = (0, 42)  [verified bit-exact in round 2]
// ---------------------------------------------------------------------------
__device__ __forceinline__ uint32_t rotl32(uint32_t x, int r) {
  return (x << r) | (x >> (32 - r));
}

__device__ __forceinline__ void threefry2x32(uint32_t x0, uint32_t x1,
                                             uint32_t& o0, uint32_t& o1) {
  const uint32_t k0 = 0u, k1 = 42u;
  const uint32_t k2 = k0 ^ k1 ^ 0x1BD11BDAu;
  x0 += k0; x1 += k1;
#define TF_ROUND(r) { x0 += x1; x1 = rotl32(x1, (r)); x1 ^= x0; }
  TF_ROUND(13) TF_ROUND(15) TF_ROUND(26) TF_ROUND(6)
  x0 += k1; x1 += k2 + 1u;
  TF_ROUND(17) TF_ROUND(29) TF_ROUND(16) TF_ROUND(24)
  x0 += k2; x1 += k0 + 2u;
  TF_ROUND(13) TF_ROUND(15) TF_ROUND(26) TF_ROUND(6)
  x0 += k0; x1 += k1 + 3u;
  TF_ROUND(17) TF_ROUND(29) TF_ROUND(16) TF_ROUND(24)
  x0 += k1; x1 += k2 + 4u;
  TF_ROUND(13) TF_ROUND(15) TF_ROUND(26) TF_ROUND(6)
  x0 += k2; x1 += k0 + 5u;
#undef TF_ROUND
  o0 = x0; o1 = x1;
}

__device__ __forceinline__ float gumbel_at(uint32_t i) {
  uint32_t o0, o1;
  threefry2x32(0u, i, o0, o1);
  uint32_t bits = o0 ^ o1;
  float f = __uint_as_float((bits >> 9) | 0x3F800000u) - 1.0f;  // [0,1)
  float u = fmaxf(1e-20f, f + 1e-20f);
  return -logf(-logf(u));
}

// monotonic float->uint mapping (IEEE total order for finite values)
__device__ __forceinline__ uint32_t fmono(float v) {
  uint32_t b = __float_as_uint(v);
  return (b & 0x80000000u) ? ~b : (b | 0x80000000u);
}

__device__ __forceinline__ unsigned short f2bf(float x) {
  __hip_bfloat16 h = __float2bfloat16(x);
  return *reinterpret_cast<unsigned short*>(&h);
}

// ---------------------------------------------------------------------------
// Generic f32 GEMM:  C[MxN] = act(A[MxK] @ W + bias),  W KxN (or NxK if BT)
// THREADS = (BM/TM)*(BN/TN)
// ---------------------------------------------------------------------------
template<int BM, int BN, int BK, int TM, int TN, int THREADS,
         bool RELU, bool BT, bool HASBIAS>
__global__ __launch_bounds__(THREADS) void gemm_kernel(
    const float* __restrict__ A, const float* __restrict__ W,
    const float* __restrict__ bias, float* __restrict__ C,
    int M, int N, int K)
{
  __shared__ __align__(16) float As[BK][BM + 4];
  __shared__ __align__(16) float Ws[BK][BN + 4];
  constexpr int TX = BN / TN;
  constexpr int TY = BM / TM;
  static_assert(TX * TY == THREADS, "bad tiling");
  constexpr int KV = BK / 4;

  const int tid = threadIdx.x;
  const int tx = tid % TX, ty = tid / TX;
  const int row0 = blockIdx.x * BM, col0 = blockIdx.y * BN;

  float acc[TM][TN];
#pragma unroll
  for (int i = 0; i < TM; ++i)
#pragma unroll
    for (int j = 0; j < TN; ++j) acc[i][j] = 0.0f;

  for (int k0 = 0; k0 < K; k0 += BK) {
#pragma unroll
    for (int e = tid; e < BM * KV; e += THREADS) {
      int m = e / KV, kq = e % KV;
      float4 v = *reinterpret_cast<const float4*>(
          &A[(size_t)(row0 + m) * K + k0 + kq * 4]);
      As[kq * 4 + 0][m] = v.x; As[kq * 4 + 1][m] = v.y;
      As[kq * 4 + 2][m] = v.z; As[kq * 4 + 3][m] = v.w;
    }
    if (BT) {
#pragma unroll
      for (int e = tid; e < BN * KV; e += THREADS) {
        int c = e / KV, kq = e % KV;
        float4 v = *reinterpret_cast<const float4*>(
            &W[(size_t)(col0 + c) * K + k0 + kq * 4]);
        Ws[kq * 4 + 0][c] = v.x; Ws[kq * 4 + 1][c] = v.y;
        Ws[kq * 4 + 2][c] = v.z; Ws[kq * 4 + 3][c] = v.w;
      }
    } else {
      constexpr int CV = BN / 4;
#pragma unroll
      for (int e = tid; e < BK * CV; e += THREADS) {
        int kk = e / CV, c4 = e % CV;
        float4 v = *reinterpret_cast<const float4*>(
            &W[(size_t)(k0 + kk) * N + col0 + c4 * 4]);
        *reinterpret_cast<float4*>(&Ws[kk][c4 * 4]) = v;
      }
    }
    __syncthreads();

#pragma unroll
    for (int kk = 0; kk < BK; ++kk) {
      float a[TM], w[TN];
#pragma unroll
      for (int i4 = 0; i4 < TM / 4; ++i4)
        *reinterpret_cast<float4*>(&a[i4 * 4]) =
            *reinterpret_cast<const float4*>(&As[kk][ty * TM + i4 * 4]);
#pragma unroll
      for (int j4 = 0; j4 < TN / 4; ++j4)
        *reinterpret_cast<float4*>(&w[j4 * 4]) =
            *reinterpret_cast<const float4*>(&Ws[kk][tx * TN + j4 * 4]);
#pragma unroll
      for (int i = 0; i < TM; ++i)
#pragma unroll
        for (int j = 0; j < TN; ++j)
          acc[i][j] = fmaf(a[i], w[j], acc[i][j]);
    }
    __syncthreads();
  }

#pragma unroll
  for (int i = 0; i < TM; ++i) {
    size_t r = (size_t)(row0 + ty * TM + i);
#pragma unroll
    for (int j4 = 0; j4 < TN / 4; ++j4) {
      int c = col0 + tx * TN + j4 * 4;
      float4 v = make_float4(acc[i][j4 * 4 + 0], acc[i][j4 * 4 + 1],
                             acc[i][j4 * 4 + 2], acc[i][j4 * 4 + 3]);
      if (HASBIAS) {
        v.x += bias[c + 0]; v.y += bias[c + 1];
        v.z += bias[c + 2]; v.w += bias[c + 3];
      }
      if (RELU) {
        v.x = fmaxf(v.x, 0.f); v.y = fmaxf(v.y, 0.f);
        v.z = fmaxf(v.z, 0.f); v.w = fmaxf(v.w, 0.f);
      }
      *reinterpret_cast<float4*>(&C[r * N + c]) = v;
    }
  }
}

// ---------------------------------------------------------------------------
// Layer-4 combined: per K-tile of h3 (K=768):
//   blockIdx.y in [0,6): pf[:, y*128 .. +128] = h3 @ W4 + b4   -> bf16
//   blockIdx.y == 6:     scores = h3 @ Ws2 + bias2 + gumbel    -> f32 [m][k]
// grid (Mc/128, 7), block 256. r0 = global row base of this chunk.
// ---------------------------------------------------------------------------
__global__ __launch_bounds__(256) void l4_combo(
    const float* __restrict__ A,        // h3 chunk [Mc][768]
    const float* __restrict__ W4, const float* __restrict__ b4,
    const float* __restrict__ Ws2, const float* __restrict__ bias2,
    unsigned short* __restrict__ pf,    // bf16 [65536][768]
    float* __restrict__ scores,         // [65536][128]
    int r0)
{
  constexpr int BM = 128, BN = 128, BK = 16, TM = 8, TN = 8;
  __shared__ __align__(16) float As[BK][BM + 4];
  __shared__ __align__(16) float Ws[BK][BN + 4];
  const int tid = threadIdx.x;
  const int tx = tid % 16, ty = tid / 16;
  const int row0 = blockIdx.x * BM;
  const bool SC = (blockIdx.y == 6);
  const float* Wp = SC ? Ws2 : W4;
  const int NW = SC ? 128 : 768;
  const int wbase = SC ? 0 : blockIdx.y * 128;

  float acc[TM][TN];
#pragma unroll
  for (int i = 0; i < TM; ++i)
#pragma unroll
    for (int j = 0; j < TN; ++j) acc[i][j] = 0.0f;

  for (int k0 = 0; k0 < 768; k0 += BK) {
#pragma unroll
    for (int e = tid; e < BM * 4; e += 256) {
      int m = e >> 2, kq = e & 3;
      float4 v = *reinterpret_cast<const float4*>(
          &A[(size_t)(row0 + m) * 768 + k0 + kq * 4]);
      As[kq * 4 + 0][m] = v.x; As[kq * 4 + 1][m] = v.y;
      As[kq * 4 + 2][m] = v.z; As[kq * 4 + 3][m] = v.w;
    }
#pragma unroll
    for (int e = tid; e < BK * 32; e += 256) {
      int kk = e >> 5, c4 = e & 31;
      float4 v = *reinterpret_cast<const float4*>(
          &Wp[(size_t)(k0 + kk) * NW + wbase + c4 * 4]);
      *reinterpret_cast<float4*>(&Ws[kk][c4 * 4]) = v;
    }
    __syncthreads();
#pragma unroll
    for (int kk = 0; kk < BK; ++kk) {
      float a[TM], w[TN];
#pragma unroll
      for (int i4 = 0; i4 < 2; ++i4)
        *reinterpret_cast<float4*>(&a[i4 * 4]) =
            *reinterpret_cast<const float4*>(&As[kk][ty * TM + i4 * 4]);
#pragma unroll
      for (int j4 = 0; j4 < 2; ++j4)
        *reinterpret_cast<float4*>(&w[j4 * 4]) =
            *reinterpret_cast<const float4*>(&Ws[kk][tx * TN + j4 * 4]);
#pragma unroll
      for (int i = 0; i < TM; ++i)
#pragma unroll
        for (int j = 0; j < TN; ++j)
          acc[i][j] = fmaf(a[i], w[j], acc[i][j]);
    }
    __syncthreads();
  }

#pragma unroll
  for (int i = 0; i < TM; ++i) {
    const int grow = r0 + row0 + ty * TM + i;
#pragma unroll
    for (int j4 = 0; j4 < 2; ++j4) {
      int lc = tx * TN + j4 * 4;
      float4 v = make_float4(acc[i][j4 * 4 + 0], acc[i][j4 * 4 + 1],
                             acc[i][j4 * 4 + 2], acc[i][j4 * 4 + 3]);
      if (!SC) {
        int c = wbase + lc;
        v.x += b4[c + 0]; v.y += b4[c + 1]; v.z += b4[c + 2]; v.w += b4[c + 3];
        ushort4 o;
        o.x = f2bf(v.x); o.y = f2bf(v.y); o.z = f2bf(v.z); o.w = f2bf(v.w);
        *reinterpret_cast<ushort4*>(&pf[(size_t)grow * 768 + c]) = o;
      } else {
        v.x += bias2[lc + 0]; v.y += bias2[lc + 1];
        v.z += bias2[lc + 2]; v.w += bias2[lc + 3];
        const uint32_t ib = ((uint32_t)(grow >> 13) << 20) | (uint32_t)(grow & 8191);
        v.x += gumbel_at(ib | ((uint32_t)(lc + 0) << 13));
        v.y += gumbel_at(ib | ((uint32_t)(lc + 1) << 13));
        v.z += gumbel_at(ib | ((uint32_t)(lc + 2) << 13));
        v.w += gumbel_at(ib | ((uint32_t)(lc + 3) << 13));
        *reinterpret_cast<float4*>(&scores[(size_t)grow * 128 + lc]) = v;
      }
    }
  }
}

// bias2[k] = sum_d b4[d] * selw[k][d]   (<<<1,128>>>)
__global__ void bias2_kernel(const float* __restrict__ b4,
                             const float* __restrict__ selw,
                             float* __restrict__ bias2) {
  int k = threadIdx.x;
  float s = 0.0f;
  for (int d = 0; d < 768; ++d) s = fmaf(b4[d], selw[(size_t)k * 768 + d], s);
  bias2[k] = s;
}

// ---------------------------------------------------------------------------
// Per-(b,k) top-32 of scores[b][:,k]+gumbel (already summed) — desc order,
// tie-break lowest m. grid (1024), block 256, 32KB LDS.
// ---------------------------------------------------------------------------
__global__ __launch_bounds__(256) void top_candidates(
    const float* __restrict__ sg, u64* __restrict__ cand)
{
  const int q = blockIdx.x;
  const int b = q >> 7, k = q & 127;
  const int tid = threadIdx.x;
  const int lane = tid & 63, wid = tid >> 6;
  __shared__ float vals[8192];
  __shared__ u64 wb[4];
  const float* base = sg + (size_t)b * 8192 * 128 + k;
  for (int j = tid; j < 8192; j += 256) vals[j] = base[(size_t)j * 128];
  __syncthreads();

  for (int it = 0; it < 32; ++it) {
    u64 loc = 0ull;
#pragma unroll
    for (int j = 0; j < 32; ++j) {
      int m = tid + j * 256;
      u64 p = ((u64)fmono(vals[m]) << 13) | (u64)(8191 - m);
      if (p > loc) loc = p;
    }
#pragma unroll
    for (int off = 32; off; off >>= 1) {
      u64 o = __shfl_down(loc, off);
      if (o > loc) loc = o;
    }
    if (lane == 0) wb[wid] = loc;
    __syncthreads();
    if (tid == 0) {
      u64 best = wb[0];
      if (wb[1] > best) best = wb[1];
      if (wb[2] > best) best = wb[2];
      if (wb[3] > best) best = wb[3];
      cand[(size_t)q * 32 + it] = best;
      vals[8191 - (int)(best & 0x1FFFull)] = __uint_as_float(0xFF800000u);
    }
    __syncthreads();
  }
}

// ---------------------------------------------------------------------------
// Sequential resolve: for k=0..127 pick first available candidate (lists are
// desc-sorted => equals masked argmax). Fallback full scan if all 32 taken.
// grid (8), block 64 (one wave).
// ---------------------------------------------------------------------------
__global__ __launch_bounds__(64) void resolve_kernel(
    const u64* __restrict__ cand, const float* __restrict__ sg,
    int* __restrict__ sel)
{
  const int b = blockIdx.x;
  const int lane = threadIdx.x;
  __shared__ uint32_t avail[256];
#pragma unroll
  for (int j = lane; j < 256; j += 64) avail[j] = 0xFFFFFFFFu;
  __syncthreads();

  for (int k = 0; k < 128; ++k) {
    u64 c = (lane < 32) ? cand[(size_t)(b * 128 + k) * 32 + lane] : 0ull;
    int m = 8191 - (int)(c & 0x1FFFull);
    bool av = (lane < 32) && ((avail[m >> 5] >> (m & 31)) & 1u);
    u64 bal = __ballot(av);
    int pick;
    if (bal) {
      int j = __builtin_ctzll(bal);
      pick = __shfl(m, j);
    } else {
      // fallback: full masked argmax over scores column k (rare/never)
      u64 best = 0ull;
      for (int mm = lane; mm < 8192; mm += 64) {
        if ((avail[mm >> 5] >> (mm & 31)) & 1u) {
          float v = sg[((size_t)b * 8192 + mm) * 128 + k];
          u64 p = ((u64)fmono(v) << 13) | (u64)(8191 - mm);
          if (p > best) best = p;
        }
      }
#pragma unroll
      for (int off = 32; off; off >>= 1) {
        u64 o = __shfl_down(best, off);
        if (o > best) best = o;
      }
      best = __shfl(best, 0);
      pick = 8191 - (int)(best & 0x1FFFull);
    }
    if (lane == 0) {
      sel[b * 128 + k] = pick;
      avail[pick >> 5] &= ~(1u << (pick & 31));
    }
    __syncthreads();
  }
}

// ---------------------------------------------------------------------------
// Per selected token: d2 to 8192 points (LDS), 16 argmin passes, fused
// feature max-pool. grid (1024), block 256.
// ---------------------------------------------------------------------------
__global__ __launch_bounds__(256) void knn_pool(
    const float* __restrict__ coords,
    const __hip_bfloat16* __restrict__ pf,
    const int* __restrict__ sel_idx,
    float* __restrict__ pooled)
{
  const int q = blockIdx.x;
  const int b = q >> 7;
  const int tid = threadIdx.x;
  const int lane = tid & 63, wid = tid >> 6;
  __shared__ float d2s[8192];
  __shared__ int nbrs[16];
  __shared__ u64 wb[4];

  const int sidx = sel_idx[q];
  const float* cbase = coords + (size_t)b * 8192 * 5;
  const float cx = cbase[sidx * 5 + 1];
  const float cy = cbase[sidx * 5 + 2];
  const float cz = cbase[sidx * 5 + 3];
  const float ss = cx * cx + cy * cy + cz * cz;

  for (int j = 0; j < 32; ++j) {
    int m = tid + j * 256;
    float px = cbase[m * 5 + 1], py = cbase[m * 5 + 2], pz = cbase[m * 5 + 3];
    d2s[m] = ss + (px * px + py * py + pz * pz)
               - 2.0f * (cx * px + cy * py + cz * pz);
  }
  __syncthreads();

  for (int it = 0; it < 16; ++it) {
    u64 loc = ~0ull;
    for (int j = 0; j < 32; ++j) {
      int m = tid + j * 256;
      u64 p = ((u64)fmono(d2s[m]) << 13) | (u64)m;
      if (p < loc) loc = p;
    }
#pragma unroll
    for (int off = 32; off; off >>= 1) {
      u64 o = __shfl_down(loc, off);
      if (o < loc) loc = o;
    }
    if (lane == 0) wb[wid] = loc;
    __syncthreads();
    if (tid == 0) {
      u64 best = wb[0];
      if (wb[1] < best) best = wb[1];
      if (wb[2] < best) best = wb[2];
      if (wb[3] < best) best = wb[3];
      int m = (int)(best & 0x1FFFull);
      nbrs[it] = m;
      d2s[m] = __uint_as_float(0x7F800000u);
    }
    __syncthreads();
  }

  for (int d = tid; d < 768; d += 256) {
    float mx = -__uint_as_float(0x7F800000u);
#pragma unroll
    for (int it = 0; it < 16; ++it) {
      float v = __bfloat162float(pf[((size_t)b * 8192 + nbrs[it]) * 768 + d]);
      mx = fmaxf(mx, v);
    }
    pooled[(size_t)q * 768 + d] = mx;
  }
}

// ---------------------------------------------------------------------------
// Stable rank-sort by time coord, write tokens/centroids/mask.
// grid (8), block 256.
// ---------------------------------------------------------------------------
__global__ __launch_bounds__(256) void finalize(
    const float* __restrict__ coords,
    const __hip_bfloat16* __restrict__ pf,
    const float* __restrict__ agg,
    const int* __restrict__ sel_idx,
    float* __restrict__ out)
{
  const int b = blockIdx.x;
  const int tid = threadIdx.x;
  __shared__ float tvals[128];
  __shared__ int rank[128];
  const float* cbase = coords + (size_t)b * 8192 * 5;

  if (tid < 128) tvals[tid] = cbase[sel_idx[(b << 7) + tid] * 5 + 4];
  __syncthreads();
  if (tid < 128) {
    float t = tvals[tid];
    int r = 0;
#pragma unroll 8
    for (int j = 0; j < 128; ++j) {
      float tj = tvals[j];
      r += (tj < t || (tj == t && j < tid)) ? 1 : 0;
    }
    rank[tid] = r;
  }
  __syncthreads();

  float* tokens = out;
  float* cent   = out + 786432;
  float* mask   = out + 786432 + 4096;

  for (int i = 0; i < 128; ++i) {
    int r = rank[i];
    int sidx = sel_idx[(b << 7) + i];
    const __hip_bfloat16* src = pf + ((size_t)b * 8192 + sidx) * 768;
    const float* asrc = agg + (size_t)((b << 7) + i) * 768;
    float* dst = tokens + ((size_t)(b << 7) + r) * 768;
    for (int d = tid; d < 768; d += 256)
      dst[d] = __bfloat162float(src[d]) + asrc[d];
  }
  if (tid < 128) {
    int r = rank[tid];
    int sidx = sel_idx[(b << 7) + tid];
    cent[((b << 7) + r) * 4 + 0] = cbase[sidx * 5 + 1];
    cent[((b << 7) + r) * 4 + 1] = cbase[sidx * 5 + 2];
    cent[((b << 7) + r) * 4 + 2] = cbase[sidx * 5 + 3];
    cent[((b << 7) + r) * 4 + 3] = cbase[sidx * 5 + 4];
    mask[(b << 7) + tid] = 1.0f;
  }
}

// ---------------------------------------------------------------------------
// host launcher
// ---------------------------------------------------------------------------
extern "C" void kernel_launch(void* const* d_in, const int* in_sizes, int n_in,
                              void* d_out, int out_size, void* d_ws, size_t ws_size,
                              hipStream_t stream) {
  const float* coords = (const float*)d_in[0];
  const float* feats  = (const float*)d_in[1];
  const float* W1 = (const float*)d_in[2];  const float* b1 = (const float*)d_in[3];
  const float* W2 = (const float*)d_in[4];  const float* b2 = (const float*)d_in[5];
  const float* W3 = (const float*)d_in[6];  const float* b3 = (const float*)d_in[7];
  const float* W4 = (const float*)d_in[8];  const float* b4 = (const float*)d_in[9];
  const float* selw = (const float*)d_in[10];
  const float* nW1 = (const float*)d_in[11]; const float* nb1 = (const float*)d_in[12];
  const float* nW2 = (const float*)d_in[13]; const float* nb2 = (const float*)d_in[14];
  float* out = (float*)d_out;

  // ---- workspace layout ----
  char* ws = (char*)d_ws;
  size_t off = 0;
  unsigned short* pf = (unsigned short*)(ws + off); off += (size_t)65536 * 768 * 2;  // 96MB
  float* scores = (float*)(ws + off);               off += (size_t)65536 * 128 * 4;  // 32MB
  float* Ws2    = (float*)(ws + off);               off += (size_t)768 * 128 * 4;
  float* bias2  = (float*)(ws + off);               off += 512;
  float* pooled = (float*)(ws + off);               off += (size_t)1024 * 768 * 4;
  float* t1     = (float*)(ws + off);               off += (size_t)1024 * 768 * 4;
  float* agg    = (float*)(ws + off);               off += (size_t)1024 * 768 * 4;
  u64*   cand   = (u64*)(ws + off);                 off += (size_t)1024 * 32 * 8;
  int*   sel    = (int*)(ws + off);                 off += 4096;
  off = (off + 255) & ~(size_t)255;
  const size_t tmp_off = off;

  int Mc = 512;
  const int mcand[8] = {65536, 32768, 16384, 8192, 4096, 2048, 1024, 512};
  for (int ci = 0; ci < 8; ++ci) {
    if (tmp_off + (size_t)6144 * mcand[ci] <= ws_size) { Mc = mcand[ci]; break; }
  }
  float* h1 = (float*)(ws + tmp_off);
  float* h2 = h1 + (size_t)Mc * 256;
  float* h3 = h2 + (size_t)Mc * 512;

  dim3 blk(256);
  // fold scores through W4: Ws2 = W4 @ selw^T, bias2 = selw @ b4
  gemm_kernel<64,64,16,4,4,256,false,true ,false>
    <<<dim3(12, 2), blk, 0, stream>>>(W4, selw, nullptr, Ws2, 768, 128, 768);
  bias2_kernel<<<1, 128, 0, stream>>>(b4, selw, bias2);

  const int nC = 65536 / Mc;
  for (int c = 0; c < nC; ++c) {
    const int r0 = c * Mc;
    gemm_kernel<128,128,16,8,8,256,true ,false,true >
      <<<dim3(Mc/128, 2), blk, 0, stream>>>(feats + (size_t)r0 * 32, W1, b1, h1, Mc, 256, 32);
    gemm_kernel<128,128,16,8,8,256,true ,false,true >
      <<<dim3(Mc/128, 4), blk, 0, stream>>>(h1, W2, b2, h2, Mc, 512, 256);
    gemm_kernel<128,128,16,8,8,256,true ,false,true >
      <<<dim3(Mc/128, 6), blk, 0, stream>>>(h2, W3, b3, h3, Mc, 768, 512);
    l4_combo<<<dim3(Mc/128, 7), blk, 0, stream>>>(h3, W4, b4, Ws2, bias2,
                                                  pf, scores, r0);
  }
  top_candidates<<<dim3(1024), blk, 0, stream>>>(scores, cand);
  resolve_kernel<<<dim3(8), dim3(64), 0, stream>>>(cand, scores, sel);
  knn_pool<<<dim3(1024), blk, 0, stream>>>(coords, (const __hip_bfloat16*)pf, sel, pooled);
  gemm_kernel<32,32,16,4,4,64,true ,false,true >
    <<<dim3(32, 24), dim3(64), 0, stream>>>(pooled, nW1, nb1, t1, 1024, 768, 768);
  gemm_kernel<32,32,16,4,4,64,false,false,true >
    <<<dim3(32, 24), dim3(64), 0, stream>>>(t1, nW2, nb2, agg, 1024, 768, 768);
  finalize<<<dim3(8), blk, 0, stream>>>(coords, (const __hip_bfloat16*)pf, agg, sel, out);
}